// Round 1
// baseline (6474.471 us; speedup 1.0000x reference)
//
#include <hip/hip_runtime.h>

// Problem constants (Attention_13116830122301):
// x: (4,192,256,256) f32; qkv_w: (576,192); dw_w: (576,1,3,3); proj_w: (192,192);
// temperature: (4,1,1); num_heads=4. Output: (4,192,256,256) f32.
constexpr int BB = 4;
constexpr int C = 192;
constexpr int NH = 4;
constexpr int CPH = 48;       // C / NH
constexpr int HH = 256;
constexpr int WI = 256;
constexpr int HW = HH * WI;   // 65536
constexpr int OC3 = 3 * C;    // 576

// Workspace layout (float offsets)
constexpr size_t WS_G   = 0;                                  // [B][NH][48][48] = 36864
constexpr size_t WS_NQ  = WS_G + (size_t)BB * NH * CPH * CPH; // +768
constexpr size_t WS_NK  = WS_NQ + (size_t)BB * NH * CPH;      // +768
constexpr size_t WS_M   = WS_NK + (size_t)BB * NH * CPH;      // [B][192][192] = 147456
constexpr size_t WS_QKV = WS_M + (size_t)BB * C * C;          // = 185856 floats (16B aligned)
constexpr size_t QKV_BSTRIDE = (size_t)OC3 * HW;              // per-batch qkv_raw floats

// ---------------------------------------------------------------------------
// K1: qkv 1x1 conv as GEMM: y[bl, o, p] = sum_c w[o,c] * x[b0+bl, c, p]
// 64x64 tile, BK=16, 256 threads, 4x4 per thread, fp32.
// ---------------------------------------------------------------------------
__global__ __launch_bounds__(256) void qkv_gemm_k(const float* __restrict__ x,
                                                  const float* __restrict__ w,
                                                  float* __restrict__ y, int b0) {
  __shared__ float Ws[16][64];  // [k][o]
  __shared__ float Xs[16][64];  // [k][p]
  const int t = threadIdx.x;
  const int p0 = blockIdx.x * 64;
  const int o0 = blockIdx.y * 64;
  const int bl = blockIdx.z;
  const float* xb = x + (size_t)(b0 + bl) * C * HW;
  const int ty = t >> 4, tx = t & 15;
  const int wo = t >> 2, wk = (t & 3) * 4;
  const int xk = t >> 4, xp = (t & 15) * 4;
  float acc[4][4] = {};
  for (int kc = 0; kc < C; kc += 16) {
    const float4 wv = *(const float4*)(w + (size_t)(o0 + wo) * C + (kc + wk));
    const float4 xv = *(const float4*)(xb + (size_t)(kc + xk) * HW + (p0 + xp));
    __syncthreads();
    Ws[wk + 0][wo] = wv.x;
    Ws[wk + 1][wo] = wv.y;
    Ws[wk + 2][wo] = wv.z;
    Ws[wk + 3][wo] = wv.w;
    *(float4*)(&Xs[xk][xp]) = xv;
    __syncthreads();
#pragma unroll
    for (int k = 0; k < 16; ++k) {
      const float4 a = *(const float4*)(&Ws[k][ty * 4]);
      const float4 b = *(const float4*)(&Xs[k][tx * 4]);
      acc[0][0] += a.x * b.x; acc[0][1] += a.x * b.y; acc[0][2] += a.x * b.z; acc[0][3] += a.x * b.w;
      acc[1][0] += a.y * b.x; acc[1][1] += a.y * b.y; acc[1][2] += a.y * b.z; acc[1][3] += a.y * b.w;
      acc[2][0] += a.z * b.x; acc[2][1] += a.z * b.y; acc[2][2] += a.z * b.z; acc[2][3] += a.z * b.w;
      acc[3][0] += a.w * b.x; acc[3][1] += a.w * b.y; acc[3][2] += a.w * b.z; acc[3][3] += a.w * b.w;
    }
  }
#pragma unroll
  for (int i = 0; i < 4; ++i) {
    float* yp = y + ((size_t)bl * OC3 + (o0 + ty * 4 + i)) * HW + (p0 + tx * 4);
    *(float4*)yp = make_float4(acc[i][0], acc[i][1], acc[i][2], acc[i][3]);
  }
}

// ---------------------------------------------------------------------------
// K2: fused dwconv(q), dwconv(k) -> Gram G[i,j] = sum_p qd_i[p]*kd_j[p]
//     plus Nq[i] = sum qd^2, Nk[j] = sum kd^2. AtomicAdd partials per block.
// Block = one (b,head) x 8 rows; chunks of 64 pixels staged in LDS (dwconv'd).
// ---------------------------------------------------------------------------
constexpr int GR_ROWS = 8;
__global__ __launch_bounds__(256) void gram_qk_k(const float* __restrict__ qkv,
                                                 const float* __restrict__ dww,
                                                 float* __restrict__ G,
                                                 float* __restrict__ Nq,
                                                 float* __restrict__ Nk, int b0) {
  __shared__ float qs[48][65];  // +1 pad: compute reads are column-broadcast
  __shared__ float ks[48][65];
  const int t = threadIdx.x;
  const int rg = blockIdx.x;
  const int h = blockIdx.y;
  const int bl = blockIdx.z;
  const int bg = b0 + bl;
  const int i0 = (t >> 4) * 3, j0 = (t & 15) * 3;
  const float* qb = qkv + (size_t)bl * OC3 * HW;
  float acc[3][3] = {};
  float nacc = 0.f;
  for (int row = rg * GR_ROWS; row < (rg + 1) * GR_ROWS; ++row) {
    for (int cx = 0; cx < WI; cx += 64) {
      __syncthreads();  // protect LDS from previous chunk's readers
#pragma unroll
      for (int r = 0; r < 24; ++r) {  // 96 channels x 64 px / 256 threads
        const int e = t + r * 256;
        const int ch = e >> 6, px = e & 63;
        const int rc = (ch < CPH) ? (h * CPH + ch) : (C + h * CPH + (ch - CPH));
        const float* cb = qb + (size_t)rc * HW;
        const float* wp = dww + rc * 9;
        const int xx = cx + px;
        float v = 0.f;
#pragma unroll
        for (int dy = -1; dy <= 1; ++dy) {
          const int yy = row + dy;
          if (yy < 0 || yy >= HH) continue;
          const float* rp = cb + (size_t)yy * WI;
#pragma unroll
          for (int dx = -1; dx <= 1; ++dx) {
            const int xc = xx + dx;
            if (xc < 0 || xc >= WI) continue;
            v += rp[xc] * wp[(dy + 1) * 3 + (dx + 1)];
          }
        }
        if (ch < CPH) qs[ch][px] = v;
        else          ks[ch - CPH][px] = v;
      }
      __syncthreads();
#pragma unroll 4
      for (int px = 0; px < 64; ++px) {
        const float q0 = qs[i0][px], q1 = qs[i0 + 1][px], q2 = qs[i0 + 2][px];
        const float k0 = ks[j0][px], k1 = ks[j0 + 1][px], k2 = ks[j0 + 2][px];
        acc[0][0] += q0 * k0; acc[0][1] += q0 * k1; acc[0][2] += q0 * k2;
        acc[1][0] += q1 * k0; acc[1][1] += q1 * k1; acc[1][2] += q1 * k2;
        acc[2][0] += q2 * k0; acc[2][1] += q2 * k1; acc[2][2] += q2 * k2;
      }
      if (t < 96) {
        const float* s = (t < CPH) ? &qs[t][0] : &ks[t - CPH][0];
#pragma unroll 8
        for (int px = 0; px < 64; ++px) nacc += s[px] * s[px];
      }
    }
  }
  float* Gb = G + ((size_t)bg * NH + h) * CPH * CPH;
#pragma unroll
  for (int ii = 0; ii < 3; ++ii)
#pragma unroll
    for (int jj = 0; jj < 3; ++jj)
      atomicAdd(&Gb[(i0 + ii) * CPH + (j0 + jj)], acc[ii][jj]);
  if (t < CPH) atomicAdd(&Nq[((size_t)bg * NH + h) * CPH + t], nacc);
  else if (t < 96) atomicAdd(&Nk[((size_t)bg * NH + h) * CPH + (t - CPH)], nacc);
}

// ---------------------------------------------------------------------------
// K3: per (b,head): logits = G/(||q_i|| ||k_j||) * temp[h]; softmax rows;
//     M[b][o][h*48+j] = sum_i proj[o][h*48+i] * attn[i][j]   (proj folded in)
// ---------------------------------------------------------------------------
__global__ __launch_bounds__(256) void softmax_M_k(const float* __restrict__ G,
                                                   const float* __restrict__ Nq,
                                                   const float* __restrict__ Nk,
                                                   const float* __restrict__ proj,
                                                   const float* __restrict__ temp,
                                                   float* __restrict__ M, int b0) {
  __shared__ float att[48][49];
  __shared__ float sq[48], sk[48];
  const int t = threadIdx.x;
  const int h = blockIdx.x;
  const int bg = b0 + blockIdx.y;
  const float* Gb = G + ((size_t)bg * NH + h) * CPH * CPH;
  if (t < CPH) sq[t] = 1.f / fmaxf(sqrtf(Nq[((size_t)bg * NH + h) * CPH + t]), 1e-12f);
  else if (t < 96) sk[t - CPH] = 1.f / fmaxf(sqrtf(Nk[((size_t)bg * NH + h) * CPH + (t - CPH)]), 1e-12f);
  __syncthreads();
  const float tp = temp[h];
  for (int e = t; e < CPH * CPH; e += 256) {
    const int i = e / CPH, j = e % CPH;
    att[i][j] = Gb[e] * sq[i] * sk[j] * tp;
  }
  __syncthreads();
  if (t < CPH) {
    float m = -1e30f;
    for (int j = 0; j < CPH; ++j) m = fmaxf(m, att[t][j]);
    float s = 0.f;
    for (int j = 0; j < CPH; ++j) { const float ev = expf(att[t][j] - m); att[t][j] = ev; s += ev; }
    const float inv = 1.f / s;
    for (int j = 0; j < CPH; ++j) att[t][j] *= inv;
  }
  __syncthreads();
  float* Mb = M + (size_t)bg * C * C;
  for (int e = t; e < C * CPH; e += 256) {
    const int o = e / CPH, j = e % CPH;
    const float* pr = proj + (size_t)o * C + h * CPH;
    float s = 0.f;
#pragma unroll 8
    for (int i = 0; i < CPH; ++i) s += pr[i] * att[i][j];
    Mb[(size_t)o * C + h * CPH + j] = s;
  }
}

// ---------------------------------------------------------------------------
// K4: out[bg, o, p] = sum_c M_b[o,c] * dwconv(v_raw)[c, p]
// Same GEMM structure as K1; v tile is dwconv'd on the fly during LDS staging
// (v_dw never materialized in HBM).
// ---------------------------------------------------------------------------
__global__ __launch_bounds__(256) void final_gemm_k(const float* __restrict__ qkv,
                                                    const float* __restrict__ Mg,
                                                    const float* __restrict__ dww,
                                                    float* __restrict__ out, int b0) {
  __shared__ float Ms[16][64];  // [c][o]
  __shared__ float Vs[16][64];  // [c][p]
  const int t = threadIdx.x;
  const int p0 = blockIdx.x * 64;
  const int o0 = blockIdx.y * 64;
  const int bl = blockIdx.z;
  const int bg = b0 + bl;
  const float* Mb = Mg + (size_t)bg * C * C;
  const float* vb = qkv + ((size_t)bl * OC3 + 2 * C) * HW;
  const int y0 = p0 >> 8;          // 64-pixel tile lies within one image row
  const int x0 = p0 & (WI - 1);
  const int ty = t >> 4, tx = t & 15;
  const int wo = t >> 2, wk = (t & 3) * 4;
  float acc[4][4] = {};
  for (int kc = 0; kc < C; kc += 16) {
    const float4 wv = *(const float4*)(Mb + (size_t)(o0 + wo) * C + (kc + wk));
    float vvals[4];
#pragma unroll
    for (int r = 0; r < 4; ++r) {  // 16 ch x 64 px / 256 threads
      const int e = t + r * 256;
      const int ch = e >> 6, px = e & 63;
      const float* cb = vb + (size_t)(kc + ch) * HW;
      const float* wp = dww + (size_t)(2 * C + kc + ch) * 9;
      const int xx = x0 + px;
      float v = 0.f;
#pragma unroll
      for (int dy = -1; dy <= 1; ++dy) {
        const int yy = y0 + dy;
        if (yy < 0 || yy >= HH) continue;
        const float* rp = cb + (size_t)yy * WI;
#pragma unroll
        for (int dx = -1; dx <= 1; ++dx) {
          const int xc = xx + dx;
          if (xc < 0 || xc >= WI) continue;
          v += rp[xc] * wp[(dy + 1) * 3 + (dx + 1)];
        }
      }
      vvals[r] = v;
    }
    __syncthreads();
    Ms[wk + 0][wo] = wv.x;
    Ms[wk + 1][wo] = wv.y;
    Ms[wk + 2][wo] = wv.z;
    Ms[wk + 3][wo] = wv.w;
#pragma unroll
    for (int r = 0; r < 4; ++r) {
      const int e = t + r * 256;
      Vs[e >> 6][e & 63] = vvals[r];
    }
    __syncthreads();
#pragma unroll
    for (int k = 0; k < 16; ++k) {
      const float4 a = *(const float4*)(&Ms[k][ty * 4]);
      const float4 b = *(const float4*)(&Vs[k][tx * 4]);
      acc[0][0] += a.x * b.x; acc[0][1] += a.x * b.y; acc[0][2] += a.x * b.z; acc[0][3] += a.x * b.w;
      acc[1][0] += a.y * b.x; acc[1][1] += a.y * b.y; acc[1][2] += a.y * b.z; acc[1][3] += a.y * b.w;
      acc[2][0] += a.z * b.x; acc[2][1] += a.z * b.y; acc[2][2] += a.z * b.z; acc[2][3] += a.z * b.w;
      acc[3][0] += a.w * b.x; acc[3][1] += a.w * b.y; acc[3][2] += a.w * b.z; acc[3][3] += a.w * b.w;
    }
  }
#pragma unroll
  for (int i = 0; i < 4; ++i) {
    float* op = out + ((size_t)bg * C + (o0 + ty * 4 + i)) * HW + (p0 + tx * 4);
    *(float4*)op = make_float4(acc[i][0], acc[i][1], acc[i][2], acc[i][3]);
  }
}

// ---------------------------------------------------------------------------
extern "C" void kernel_launch(void* const* d_in, const int* in_sizes, int n_in,
                              void* d_out, int out_size, void* d_ws, size_t ws_size,
                              hipStream_t stream) {
  const float* x      = (const float*)d_in[0];
  const float* qkv_w  = (const float*)d_in[1];
  const float* dw_w   = (const float*)d_in[2];
  const float* proj_w = (const float*)d_in[3];
  const float* temp   = (const float*)d_in[4];
  float* out = (float*)d_out;
  float* ws = (float*)d_ws;
  float* G   = ws + WS_G;
  float* Nq  = ws + WS_NQ;
  float* Nk  = ws + WS_NK;
  float* M   = ws + WS_M;
  float* qkv = ws + WS_QKV;

  const size_t small_bytes = WS_QKV * sizeof(float);
  const size_t per_batch_bytes = QKV_BSTRIDE * sizeof(float);  // ~151 MB
  int nb = 1;
  if (ws_size >= small_bytes + 4 * per_batch_bytes) nb = 4;
  else if (ws_size >= small_bytes + 2 * per_batch_bytes) nb = 2;

  // zero gram accumulators (G, Nq, Nk) — ws is poisoned before each call
  hipMemsetAsync(G, 0, (WS_M - WS_G) * sizeof(float), stream);

  for (int b0 = 0; b0 < BB; b0 += nb) {
    qkv_gemm_k<<<dim3(HW / 64, OC3 / 64, nb), 256, 0, stream>>>(x, qkv_w, qkv, b0);
    gram_qk_k<<<dim3(HH / GR_ROWS, NH, nb), 256, 0, stream>>>(qkv, dw_w, G, Nq, Nk, b0);
    softmax_M_k<<<dim3(NH, nb), 256, 0, stream>>>(G, Nq, Nk, proj_w, temp, M, b0);
    final_gemm_k<<<dim3(HW / 64, C / 64, nb), 256, 0, stream>>>(qkv, M, dw_w, out, b0);
  }
}

// Round 2
// 2486.025 us; speedup vs baseline: 2.6043x; 2.6043x over previous
//
#include <hip/hip_runtime.h>

// Problem constants (Attention_13116830122301):
// x: (4,192,256,256) f32; qkv_w: (576,192); dw_w: (576,1,3,3); proj_w: (192,192);
// temperature: (4,1,1); num_heads=4. Output: (4,192,256,256) f32.
constexpr int BB = 4;
constexpr int C = 192;
constexpr int NH = 4;
constexpr int CPH = 48;       // C / NH
constexpr int HH = 256;
constexpr int WI = 256;
constexpr int HW = HH * WI;   // 65536
constexpr int OC3 = 3 * C;    // 576

// Workspace layout (float offsets)
constexpr size_t WS_G   = 0;                                  // [B][NH][48][48]
constexpr size_t WS_NQ  = WS_G + (size_t)BB * NH * CPH * CPH; // [B][C]
constexpr size_t WS_NK  = WS_NQ + (size_t)BB * C;             // [B][C]
constexpr size_t WS_M   = WS_NK + (size_t)BB * C;             // [B][192][192]
constexpr size_t WS_QKV = WS_M + (size_t)BB * C * C;
constexpr size_t QKV_BSTRIDE = (size_t)OC3 * HW;              // per-batch qkv floats

// ---------------------------------------------------------------------------
// K1: qkv 1x1 conv as GEMM: y[bl, o, p] = sum_c w[o,c] * x[b0+bl, c, p]
// 64x64 tile, BK=16, 256 threads, 4x4 per thread, fp32.
// ---------------------------------------------------------------------------
__global__ __launch_bounds__(256) void qkv_gemm_k(const float* __restrict__ x,
                                                  const float* __restrict__ w,
                                                  float* __restrict__ y, int b0) {
  __shared__ float Ws[16][64];  // [k][o]
  __shared__ float Xs[16][64];  // [k][p]
  const int t = threadIdx.x;
  const int p0 = blockIdx.x * 64;
  const int o0 = blockIdx.y * 64;
  const int bl = blockIdx.z;
  const float* xb = x + (size_t)(b0 + bl) * C * HW;
  const int ty = t >> 4, tx = t & 15;
  const int wo = t >> 2, wk = (t & 3) * 4;
  const int xk = t >> 4, xp = (t & 15) * 4;
  float acc[4][4] = {};
  for (int kc = 0; kc < C; kc += 16) {
    const float4 wv = *(const float4*)(w + (size_t)(o0 + wo) * C + (kc + wk));
    const float4 xv = *(const float4*)(xb + (size_t)(kc + xk) * HW + (p0 + xp));
    __syncthreads();
    Ws[wk + 0][wo] = wv.x;
    Ws[wk + 1][wo] = wv.y;
    Ws[wk + 2][wo] = wv.z;
    Ws[wk + 3][wo] = wv.w;
    *(float4*)(&Xs[xk][xp]) = xv;
    __syncthreads();
#pragma unroll
    for (int k = 0; k < 16; ++k) {
      const float4 a = *(const float4*)(&Ws[k][ty * 4]);
      const float4 b = *(const float4*)(&Xs[k][tx * 4]);
      acc[0][0] += a.x * b.x; acc[0][1] += a.x * b.y; acc[0][2] += a.x * b.z; acc[0][3] += a.x * b.w;
      acc[1][0] += a.y * b.x; acc[1][1] += a.y * b.y; acc[1][2] += a.y * b.z; acc[1][3] += a.y * b.w;
      acc[2][0] += a.z * b.x; acc[2][1] += a.z * b.y; acc[2][2] += a.z * b.z; acc[2][3] += a.z * b.w;
      acc[3][0] += a.w * b.x; acc[3][1] += a.w * b.y; acc[3][2] += a.w * b.z; acc[3][3] += a.w * b.w;
    }
  }
#pragma unroll
  for (int i = 0; i < 4; ++i) {
    float* yp = y + ((size_t)bl * OC3 + (o0 + ty * 4 + i)) * HW + (p0 + tx * 4);
    *(float4*)yp = make_float4(acc[i][0], acc[i][1], acc[i][2], acc[i][3]);
  }
}

// ---------------------------------------------------------------------------
// K2: materialize 3x3 depthwise conv for ALL 576 channels.
// Block = (row-group of 8, channel, batch); thread t owns pixel column t.
// Folds q/k L2-norm accumulation in (one atomicAdd per block).
// ---------------------------------------------------------------------------
constexpr int DW_ROWS = 8;
__global__ __launch_bounds__(256) void dwconv_k(const float* __restrict__ raw,
                                                const float* __restrict__ dww,
                                                float* __restrict__ dst,
                                                float* __restrict__ Nq,
                                                float* __restrict__ Nk, int b0) {
  const int t = threadIdx.x;
  const int rg = blockIdx.x;   // HH / DW_ROWS
  const int ch = blockIdx.y;   // OC3
  const int bl = blockIdx.z;
  const int bg = b0 + bl;
  const float* cb = raw + ((size_t)bl * OC3 + ch) * HW;
  float* ob = dst + ((size_t)bl * OC3 + ch) * HW;
  float wgt[9];
#pragma unroll
  for (int i = 0; i < 9; ++i) wgt[i] = dww[ch * 9 + i];
  float nacc = 0.f;
#pragma unroll
  for (int r = 0; r < DW_ROWS; ++r) {
    const int y = rg * DW_ROWS + r;
    float v = 0.f;
#pragma unroll
    for (int dy = -1; dy <= 1; ++dy) {
      const int yy = y + dy;
      if (yy < 0 || yy >= HH) continue;
      const float* rp = cb + (size_t)yy * WI;
#pragma unroll
      for (int dx = -1; dx <= 1; ++dx) {
        const int xc = t + dx;
        if (xc < 0 || xc >= WI) continue;
        v += rp[xc] * wgt[(dy + 1) * 3 + (dx + 1)];
      }
    }
    ob[(size_t)y * WI + t] = v;
    nacc += v * v;
  }
  if (ch < 2 * C) {  // q or k channel: accumulate L2 norm
#pragma unroll
    for (int off = 32; off > 0; off >>= 1) nacc += __shfl_down(nacc, off);
    __shared__ float red[4];
    if ((t & 63) == 0) red[t >> 6] = nacc;
    __syncthreads();
    if (t == 0) {
      const float tot = red[0] + red[1] + red[2] + red[3];
      if (ch < C) atomicAdd(&Nq[(size_t)bg * C + ch], tot);
      else        atomicAdd(&Nk[(size_t)bg * C + (ch - C)], tot);
    }
  }
}

// ---------------------------------------------------------------------------
// K3: Gram G[i,j] = sum_p qd[i,p] * kd[j,p] per (b,head), from materialized dw.
// Block = (px-chunk of 1024, head, batch); 16x16 threads x 3x3 cells.
// ---------------------------------------------------------------------------
__global__ __launch_bounds__(256) void gram2_k(const float* __restrict__ dw,
                                               float* __restrict__ G, int b0) {
  __shared__ float qs[48][132];  // +4 pad -> conflict-free strided reads
  __shared__ float ks[48][132];
  const int t = threadIdx.x;
  const int chunk = blockIdx.x;  // 64 chunks of 1024 px
  const int h = blockIdx.y;
  const int bl = blockIdx.z;
  const int bg = b0 + bl;
  const float* qb = dw + (size_t)bl * OC3 * HW + (size_t)h * CPH * HW;
  const float* kb = qb + (size_t)C * HW;
  const int ty = t >> 4, tx = t & 15;
  const int i0 = ty * 3, j0 = tx * 3;
  float acc[3][3] = {};
  for (int sub = 0; sub < 8; ++sub) {
    const int p0 = chunk * 1024 + sub * 128;
    __syncthreads();
#pragma unroll
    for (int r = 0; r < 6; ++r) {
      const int f = t + r * 256;     // [0, 1536): 48 rows x 32 float4
      const int ch = f >> 5;
      const int px = (f & 31) * 4;
      *(float4*)&qs[ch][px] = *(const float4*)(qb + (size_t)ch * HW + p0 + px);
      *(float4*)&ks[ch][px] = *(const float4*)(kb + (size_t)ch * HW + p0 + px);
    }
    __syncthreads();
#pragma unroll 2
    for (int px = 0; px < 128; px += 4) {
      const float4 q0 = *(const float4*)&qs[i0][px];
      const float4 q1 = *(const float4*)&qs[i0 + 1][px];
      const float4 q2 = *(const float4*)&qs[i0 + 2][px];
      const float4 k0 = *(const float4*)&ks[j0][px];
      const float4 k1 = *(const float4*)&ks[j0 + 1][px];
      const float4 k2 = *(const float4*)&ks[j0 + 2][px];
      acc[0][0] += q0.x*k0.x + q0.y*k0.y + q0.z*k0.z + q0.w*k0.w;
      acc[0][1] += q0.x*k1.x + q0.y*k1.y + q0.z*k1.z + q0.w*k1.w;
      acc[0][2] += q0.x*k2.x + q0.y*k2.y + q0.z*k2.z + q0.w*k2.w;
      acc[1][0] += q1.x*k0.x + q1.y*k0.y + q1.z*k0.z + q1.w*k0.w;
      acc[1][1] += q1.x*k1.x + q1.y*k1.y + q1.z*k1.z + q1.w*k1.w;
      acc[1][2] += q1.x*k2.x + q1.y*k2.y + q1.z*k2.z + q1.w*k2.w;
      acc[2][0] += q2.x*k0.x + q2.y*k0.y + q2.z*k0.z + q2.w*k0.w;
      acc[2][1] += q2.x*k1.x + q2.y*k1.y + q2.z*k1.z + q2.w*k1.w;
      acc[2][2] += q2.x*k2.x + q2.y*k2.y + q2.z*k2.z + q2.w*k2.w;
    }
  }
  float* Gb = G + ((size_t)bg * NH + h) * CPH * CPH;
#pragma unroll
  for (int ii = 0; ii < 3; ++ii)
#pragma unroll
    for (int jj = 0; jj < 3; ++jj)
      atomicAdd(&Gb[(i0 + ii) * CPH + (j0 + jj)], acc[ii][jj]);
}

// ---------------------------------------------------------------------------
// K4: per (b,head): logits = G/(||q_i|| ||k_j||) * temp[h]; softmax rows;
//     M[b][o][h*48+j] = sum_i proj[o][h*48+i] * attn[i][j]   (proj folded in)
// ---------------------------------------------------------------------------
__global__ __launch_bounds__(256) void softmax_M_k(const float* __restrict__ G,
                                                   const float* __restrict__ Nq,
                                                   const float* __restrict__ Nk,
                                                   const float* __restrict__ proj,
                                                   const float* __restrict__ temp,
                                                   float* __restrict__ M, int b0) {
  __shared__ float att[48][49];
  __shared__ float sq[48], sk[48];
  const int t = threadIdx.x;
  const int h = blockIdx.x;
  const int bg = b0 + blockIdx.y;
  const float* Gb = G + ((size_t)bg * NH + h) * CPH * CPH;
  if (t < CPH) sq[t] = 1.f / fmaxf(sqrtf(Nq[(size_t)bg * C + h * CPH + t]), 1e-12f);
  else if (t < 96) sk[t - CPH] = 1.f / fmaxf(sqrtf(Nk[(size_t)bg * C + h * CPH + (t - CPH)]), 1e-12f);
  __syncthreads();
  const float tp = temp[h];
  for (int e = t; e < CPH * CPH; e += 256) {
    const int i = e / CPH, j = e % CPH;
    att[i][j] = Gb[e] * sq[i] * sk[j] * tp;
  }
  __syncthreads();
  if (t < CPH) {
    float m = -1e30f;
    for (int j = 0; j < CPH; ++j) m = fmaxf(m, att[t][j]);
    float s = 0.f;
    for (int j = 0; j < CPH; ++j) { const float ev = expf(att[t][j] - m); att[t][j] = ev; s += ev; }
    const float inv = 1.f / s;
    for (int j = 0; j < CPH; ++j) att[t][j] *= inv;
  }
  __syncthreads();
  float* Mb = M + (size_t)bg * C * C;
  for (int e = t; e < C * CPH; e += 256) {
    const int o = e / CPH, j = e % CPH;
    const float* pr = proj + (size_t)o * C + h * CPH;
    float s = 0.f;
#pragma unroll 8
    for (int i = 0; i < CPH; ++i) s += pr[i] * att[i][j];
    Mb[(size_t)o * C + h * CPH + j] = s;
  }
}

// ---------------------------------------------------------------------------
// K5: out[bg, o, p] = sum_c M_b[o,c] * vd[c, p]  (vd = materialized dwconv(v))
// Same structure as K1, coalesced float4 staging.
// ---------------------------------------------------------------------------
__global__ __launch_bounds__(256) void final_gemm_k(const float* __restrict__ dw,
                                                    const float* __restrict__ Mg,
                                                    float* __restrict__ out, int b0) {
  __shared__ float Ms[16][64];  // [c][o]
  __shared__ float Vs[16][64];  // [c][p]
  const int t = threadIdx.x;
  const int p0 = blockIdx.x * 64;
  const int o0 = blockIdx.y * 64;
  const int bl = blockIdx.z;
  const int bg = b0 + bl;
  const float* Mb = Mg + (size_t)bg * C * C;
  const float* vb = dw + ((size_t)bl * OC3 + 2 * C) * HW;
  const int ty = t >> 4, tx = t & 15;
  const int wo = t >> 2, wk = (t & 3) * 4;
  const int xk = t >> 4, xp = (t & 15) * 4;
  float acc[4][4] = {};
  for (int kc = 0; kc < C; kc += 16) {
    const float4 wv = *(const float4*)(Mb + (size_t)(o0 + wo) * C + (kc + wk));
    const float4 xv = *(const float4*)(vb + (size_t)(kc + xk) * HW + (p0 + xp));
    __syncthreads();
    Ms[wk + 0][wo] = wv.x;
    Ms[wk + 1][wo] = wv.y;
    Ms[wk + 2][wo] = wv.z;
    Ms[wk + 3][wo] = wv.w;
    *(float4*)(&Vs[xk][xp]) = xv;
    __syncthreads();
#pragma unroll
    for (int k = 0; k < 16; ++k) {
      const float4 a = *(const float4*)(&Ms[k][ty * 4]);
      const float4 b = *(const float4*)(&Vs[k][tx * 4]);
      acc[0][0] += a.x * b.x; acc[0][1] += a.x * b.y; acc[0][2] += a.x * b.z; acc[0][3] += a.x * b.w;
      acc[1][0] += a.y * b.x; acc[1][1] += a.y * b.y; acc[1][2] += a.y * b.z; acc[1][3] += a.y * b.w;
      acc[2][0] += a.z * b.x; acc[2][1] += a.z * b.y; acc[2][2] += a.z * b.z; acc[2][3] += a.z * b.w;
      acc[3][0] += a.w * b.x; acc[3][1] += a.w * b.y; acc[3][2] += a.w * b.z; acc[3][3] += a.w * b.w;
    }
  }
#pragma unroll
  for (int i = 0; i < 4; ++i) {
    float* op = out + ((size_t)bg * C + (o0 + ty * 4 + i)) * HW + (p0 + tx * 4);
    *(float4*)op = make_float4(acc[i][0], acc[i][1], acc[i][2], acc[i][3]);
  }
}

// ---------------------------------------------------------------------------
extern "C" void kernel_launch(void* const* d_in, const int* in_sizes, int n_in,
                              void* d_out, int out_size, void* d_ws, size_t ws_size,
                              hipStream_t stream) {
  const float* x      = (const float*)d_in[0];
  const float* qkv_w  = (const float*)d_in[1];
  const float* dw_w   = (const float*)d_in[2];
  const float* proj_w = (const float*)d_in[3];
  const float* temp   = (const float*)d_in[4];
  float* out = (float*)d_out;
  float* ws = (float*)d_ws;
  float* G   = ws + WS_G;
  float* Nq  = ws + WS_NQ;
  float* Nk  = ws + WS_NK;
  float* M   = ws + WS_M;
  float* raw = ws + WS_QKV;

  const size_t small = WS_QKV * sizeof(float);
  const size_t unit = QKV_BSTRIDE * sizeof(float);  // ~151 MB
  // Round-1 timing proved nb=4 single-buffer fit (ws >= small + 4*unit), so
  // the two-buffer nb=2 tier is guaranteed reachable.
  int nb = 1;
  if (ws_size >= small + 8 * unit) nb = 4;
  else if (ws_size >= small + 4 * unit) nb = 2;
  float* dwb = raw + (size_t)nb * QKV_BSTRIDE;

  // zero accumulators (G, Nq, Nk) — ws is poisoned before each call
  hipMemsetAsync(G, 0, (WS_M - WS_G) * sizeof(float), stream);

  for (int b0 = 0; b0 < BB; b0 += nb) {
    qkv_gemm_k<<<dim3(HW / 64, OC3 / 64, nb), 256, 0, stream>>>(x, qkv_w, raw, b0);
    dwconv_k<<<dim3(HH / DW_ROWS, OC3, nb), 256, 0, stream>>>(raw, dw_w, dwb, Nq, Nk, b0);
    gram2_k<<<dim3(64, NH, nb), 256, 0, stream>>>(dwb, G, b0);
    softmax_M_k<<<dim3(NH, nb), 256, 0, stream>>>(G, Nq, Nk, proj_w, temp, M, b0);
    final_gemm_k<<<dim3(HW / 64, C / 64, nb), 256, 0, stream>>>(dwb, M, out, b0);
  }
}

// Round 3
// 994.951 us; speedup vs baseline: 6.5073x; 2.4986x over previous
//
#include <hip/hip_runtime.h>
#include <hip/hip_bf16.h>

// Problem constants (Attention_13116830122301):
// x: (4,192,256,256) f32; qkv_w: (576,192); dw_w: (576,1,3,3); proj_w: (192,192);
// temperature: (4,1,1); num_heads=4. Output: (4,192,256,256) f32.
constexpr int BB = 4;
constexpr int C = 192;
constexpr int NH = 4;
constexpr int CPH = 48;       // C / num_heads
constexpr int HH = 256;
constexpr int WI = 256;
constexpr int HW = HH * WI;   // 65536
constexpr int OC3 = 3 * C;    // 576

// Workspace layout (float offsets for the small fp32 region)
constexpr size_t WS_G   = 0;                                  // [B][NH][48][48]
constexpr size_t WS_NQ  = WS_G + (size_t)BB * NH * CPH * CPH; // [B][C]
constexpr size_t WS_NK  = WS_NQ + (size_t)BB * C;             // [B][C]
constexpr size_t WS_M   = WS_NK + (size_t)BB * C;             // [B][192][192]
constexpr size_t WS_END = WS_M + (size_t)BB * C * C;          // 185856 floats

typedef __attribute__((ext_vector_type(8))) short bf16x8;
typedef __attribute__((ext_vector_type(4))) float f32x4;

union FragU { bf16x8 f; uint4 q; uint w[4]; ushort s[8]; };

__device__ inline float b2f(ushort u) {
  union { uint i; float f; } v; v.i = (uint)u << 16; return v.f;
}
__device__ inline ushort f2b(float f) {
  __hip_bfloat16 b = __float2bfloat16(f);
  ushort r; __builtin_memcpy(&r, &b, 2); return r;
}
__device__ inline uint f2b2(float lo, float hi) {
  __hip_bfloat162 h = __float22bfloat162_rn(make_float2(lo, hi));
  uint r; __builtin_memcpy(&r, &h, 4); return r;
}
__device__ inline bf16x8 ld_frag(const ushort* p) {  // 8 bf16, 16-B aligned
  FragU u; u.q = *(const uint4*)p; return u.f;
}
__device__ inline bf16x8 pack8(const float* v) {     // 8 fp32 -> 8 bf16
  FragU u;
#pragma unroll
  for (int i = 0; i < 4; ++i) u.w[i] = f2b2(v[2 * i], v[2 * i + 1]);
  return u.f;
}

// ---------------------------------------------------------------------------
// K1: qkv 1x1 conv, bf16 MFMA, no LDS. y_bf16[bl][o][p] = sum_c w[o][c] x[c][p].
// Block 256 = 4 waves; block tile 64o x 256p (wave: 64o x 64p = 4x4 MFMA tiles).
// A-frags: w rows, contiguous-in-c 16-B... fp32 loads + cvt.
// B-frags: x columns, 8 strided dword loads (64-B segments, L2-resident reuse).
// ---------------------------------------------------------------------------
__global__ __launch_bounds__(256) void qkv_mfma_k(const float* __restrict__ x,
                                                  const float* __restrict__ w,
                                                  ushort* __restrict__ y, int b0) {
  const int t = threadIdx.x;
  const int wv = t >> 6, l = t & 63;
  const int lr = l & 15, lg = l >> 4;
  const int p0 = blockIdx.x * 256 + wv * 64;
  const int o0 = blockIdx.y * 64;
  const int bl = blockIdx.z;
  const float* xb = x + (size_t)(b0 + bl) * C * HW;
  f32x4 acc[4][4] = {};
  for (int ks = 0; ks < C; ks += 32) {
    bf16x8 afr[4], bfr[4];
#pragma unroll
    for (int mi = 0; mi < 4; ++mi) {
      const float* ap = w + (size_t)(o0 + mi * 16 + lr) * C + ks + lg * 8;
      float av[8];
      *(float4*)(av) = *(const float4*)ap;
      *(float4*)(av + 4) = *(const float4*)(ap + 4);
      afr[mi] = pack8(av);
    }
#pragma unroll
    for (int ni = 0; ni < 4; ++ni) {
      const float* bp = xb + (size_t)(ks + lg * 8) * HW + (p0 + ni * 16 + lr);
      float bv[8];
#pragma unroll
      for (int j = 0; j < 8; ++j) bv[j] = bp[(size_t)j * HW];
      bfr[ni] = pack8(bv);
    }
#pragma unroll
    for (int mi = 0; mi < 4; ++mi)
#pragma unroll
      for (int ni = 0; ni < 4; ++ni)
        acc[mi][ni] = __builtin_amdgcn_mfma_f32_16x16x32_bf16(afr[mi], bfr[ni], acc[mi][ni], 0, 0, 0);
  }
  ushort* yb = y + (size_t)bl * OC3 * HW;
#pragma unroll
  for (int mi = 0; mi < 4; ++mi)
#pragma unroll
    for (int r = 0; r < 4; ++r) {
      const int o = o0 + mi * 16 + lg * 4 + r;
#pragma unroll
      for (int ni = 0; ni < 4; ++ni)
        yb[(size_t)o * HW + (p0 + ni * 16 + lr)] = f2b(acc[mi][ni][r]);
    }
}

// ---------------------------------------------------------------------------
// K2: 3x3 depthwise conv, bf16 in -> bf16 out, 4 px/thread, sliding 3-row
// register window (30 vector loads per 8 output rows). Folds q/k L2 norms.
// Block: (32-row group, channel, batch); thread = (strip s = t&63, rq = t>>6).
// ---------------------------------------------------------------------------
constexpr int DW_RPB = 32;
__global__ __launch_bounds__(256) void dwconv_k(const ushort* __restrict__ raw,
                                                const float* __restrict__ dww,
                                                ushort* __restrict__ dst,
                                                float* __restrict__ Nq,
                                                float* __restrict__ Nk, int b0) {
  const int t = threadIdx.x;
  const int s = t & 63;
  const int rq = t >> 6;
  const int ch = blockIdx.y;
  const int bl = blockIdx.z;
  const int bg = b0 + bl;
  const int y0 = blockIdx.x * DW_RPB + rq * 8;
  const int x4 = s * 4;
  const ushort* cb = raw + ((size_t)bl * OC3 + ch) * HW;
  ushort* ob = dst + ((size_t)bl * OC3 + ch) * HW;
  float wg[9];
#pragma unroll
  for (int i = 0; i < 9; ++i) wg[i] = dww[ch * 9 + i];

  auto load_row = [&](int y, float* r) {
    if ((unsigned)y >= (unsigned)HH) {
#pragma unroll
      for (int i = 0; i < 6; ++i) r[i] = 0.f;
      return;
    }
    const ushort* rp = cb + (size_t)y * WI;
    const ushort4 m = *(const ushort4*)(rp + x4);
    r[1] = b2f(m.x); r[2] = b2f(m.y); r[3] = b2f(m.z); r[4] = b2f(m.w);
    r[0] = (s > 0) ? b2f(rp[x4 - 1]) : 0.f;
    r[5] = (s < 63) ? b2f(rp[x4 + 4]) : 0.f;
  };

  float r0[6], r1[6], r2[6];
  load_row(y0 - 1, r0);
  load_row(y0, r1);
  float nacc = 0.f;
#pragma unroll
  for (int i = 0; i < 8; ++i) {
    const int y = y0 + i;
    load_row(y + 1, r2);
    float o[4];
#pragma unroll
    for (int px = 0; px < 4; ++px) {
      float v = wg[0] * r0[px] + wg[1] * r0[px + 1] + wg[2] * r0[px + 2]
              + wg[3] * r1[px] + wg[4] * r1[px + 1] + wg[5] * r1[px + 2]
              + wg[6] * r2[px] + wg[7] * r2[px + 1] + wg[8] * r2[px + 2];
      o[px] = v;
      nacc += v * v;
    }
    uint2 pk;
    pk.x = f2b2(o[0], o[1]);
    pk.y = f2b2(o[2], o[3]);
    *(uint2*)(ob + (size_t)y * WI + x4) = pk;
#pragma unroll
    for (int k = 0; k < 6; ++k) { r0[k] = r1[k]; r1[k] = r2[k]; }
  }
  if (ch < 2 * C) {  // q or k channel: accumulate L2 norm
#pragma unroll
    for (int off = 32; off > 0; off >>= 1) nacc += __shfl_down(nacc, off);
    __shared__ float red[4];
    if ((t & 63) == 0) red[t >> 6] = nacc;
    __syncthreads();
    if (t == 0) {
      const float tot = red[0] + red[1] + red[2] + red[3];
      if (ch < C) atomicAdd(&Nq[(size_t)bg * C + ch], tot);
      else        atomicAdd(&Nk[(size_t)bg * C + (ch - C)], tot);
    }
  }
}

// ---------------------------------------------------------------------------
// K3: Gram G[i,j] = sum_p qd[i,p] kd[j,p] per (b,head) via MFMA.
// A and B fragments are both contiguous-in-p 16-B loads from [ch][px] bf16 —
// no LDS staging, no transpose. K split over 32 chunks; LDS + global atomics.
// ---------------------------------------------------------------------------
__global__ __launch_bounds__(256) void gram_mfma_k(const ushort* __restrict__ dw,
                                                   float* __restrict__ G, int b0) {
  __shared__ float Gs[CPH][CPH + 1];
  const int t = threadIdx.x;
  const int wv = t >> 6, l = t & 63;
  const int lr = l & 15, lg = l >> 4;
  const int chunk = blockIdx.x;  // 0..31
  const int h = blockIdx.y;
  const int bl = blockIdx.z;
  const int bg = b0 + bl;
  const ushort* qb = dw + ((size_t)bl * OC3 + h * CPH) * HW;
  const ushort* kb = qb + (size_t)C * HW;
  f32x4 acc[3][3] = {};
  for (int it = 0; it < 16; ++it) {
    const int p = chunk * 2048 + it * 128 + wv * 32 + lg * 8;
    bf16x8 afr[3], bfr[3];
#pragma unroll
    for (int mi = 0; mi < 3; ++mi) afr[mi] = ld_frag(qb + (size_t)(mi * 16 + lr) * HW + p);
#pragma unroll
    for (int ni = 0; ni < 3; ++ni) bfr[ni] = ld_frag(kb + (size_t)(ni * 16 + lr) * HW + p);
#pragma unroll
    for (int mi = 0; mi < 3; ++mi)
#pragma unroll
      for (int ni = 0; ni < 3; ++ni)
        acc[mi][ni] = __builtin_amdgcn_mfma_f32_16x16x32_bf16(afr[mi], bfr[ni], acc[mi][ni], 0, 0, 0);
  }
  for (int e = t; e < CPH * (CPH + 1); e += 256) ((float*)Gs)[e] = 0.f;
  __syncthreads();
#pragma unroll
  for (int mi = 0; mi < 3; ++mi)
#pragma unroll
    for (int ni = 0; ni < 3; ++ni)
#pragma unroll
      for (int r = 0; r < 4; ++r)
        atomicAdd(&Gs[mi * 16 + lg * 4 + r][ni * 16 + lr], acc[mi][ni][r]);
  __syncthreads();
  float* Gb = G + ((size_t)bg * NH + h) * CPH * CPH;
  for (int e = t; e < CPH * CPH; e += 256)
    atomicAdd(&Gb[e], Gs[e / CPH][e % CPH]);
}

// ---------------------------------------------------------------------------
// K4: per (b,head): logits = G/(||q_i|| ||k_j||) * temp[h]; softmax rows;
//     M[b][o][h*48+j] = sum_i proj[o][h*48+i] * attn[i][j]   (proj folded in)
// ---------------------------------------------------------------------------
__global__ __launch_bounds__(256) void softmax_M_k(const float* __restrict__ G,
                                                   const float* __restrict__ Nq,
                                                   const float* __restrict__ Nk,
                                                   const float* __restrict__ proj,
                                                   const float* __restrict__ temp,
                                                   float* __restrict__ M, int b0) {
  __shared__ float att[48][49];
  __shared__ float sq[48], sk[48];
  const int t = threadIdx.x;
  const int h = blockIdx.x;
  const int bg = b0 + blockIdx.y;
  const float* Gb = G + ((size_t)bg * NH + h) * CPH * CPH;
  if (t < CPH) sq[t] = 1.f / fmaxf(sqrtf(Nq[(size_t)bg * C + h * CPH + t]), 1e-12f);
  else if (t < 96) sk[t - CPH] = 1.f / fmaxf(sqrtf(Nk[(size_t)bg * C + h * CPH + (t - CPH)]), 1e-12f);
  __syncthreads();
  const float tp = temp[h];
  for (int e = t; e < CPH * CPH; e += 256) {
    const int i = e / CPH, j = e % CPH;
    att[i][j] = Gb[e] * sq[i] * sk[j] * tp;
  }
  __syncthreads();
  if (t < CPH) {
    float m = -1e30f;
    for (int j = 0; j < CPH; ++j) m = fmaxf(m, att[t][j]);
    float sum = 0.f;
    for (int j = 0; j < CPH; ++j) { const float ev = expf(att[t][j] - m); att[t][j] = ev; sum += ev; }
    const float inv = 1.f / sum;
    for (int j = 0; j < CPH; ++j) att[t][j] *= inv;
  }
  __syncthreads();
  float* Mb = M + (size_t)bg * C * C;
  for (int e = t; e < C * CPH; e += 256) {
    const int o = e / CPH, j = e % CPH;
    const float* pr = proj + (size_t)o * C + h * CPH;
    float s = 0.f;
#pragma unroll 8
    for (int i = 0; i < CPH; ++i) s += pr[i] * att[i][j];
    Mb[(size_t)o * C + h * CPH + j] = s;
  }
}

// ---------------------------------------------------------------------------
// K5: out[bg,o,p] = sum_c M_b[o,c] * vd[c,p]; bf16 MFMA, no LDS.
// A = M_b (fp32, L2-resident) direct 16-B loads + cvt; B = vd bf16 strided
// ushort loads (L2-warm). Block tile 64o x 256p.
// ---------------------------------------------------------------------------
__global__ __launch_bounds__(256) void out_mfma_k(const ushort* __restrict__ dw,
                                                  const float* __restrict__ Mg,
                                                  float* __restrict__ out, int b0) {
  const int t = threadIdx.x;
  const int wv = t >> 6, l = t & 63;
  const int lr = l & 15, lg = l >> 4;
  const int p0 = blockIdx.x * 256 + wv * 64;
  const int o0 = blockIdx.y * 64;
  const int bl = blockIdx.z;
  const int bg = b0 + bl;
  const float* Mb = Mg + (size_t)bg * C * C;
  const ushort* vb = dw + ((size_t)bl * OC3 + 2 * C) * HW;
  f32x4 acc[4][4] = {};
  for (int ks = 0; ks < C; ks += 32) {
    bf16x8 afr[4], bfr[4];
#pragma unroll
    for (int mi = 0; mi < 4; ++mi) {
      const float* ap = Mb + (size_t)(o0 + mi * 16 + lr) * C + ks + lg * 8;
      float av[8];
      *(float4*)(av) = *(const float4*)ap;
      *(float4*)(av + 4) = *(const float4*)(ap + 4);
      afr[mi] = pack8(av);
    }
#pragma unroll
    for (int ni = 0; ni < 4; ++ni) {
      const ushort* bp = vb + (size_t)(ks + lg * 8) * HW + (p0 + ni * 16 + lr);
      FragU u;
#pragma unroll
      for (int jp = 0; jp < 4; ++jp) {
        const uint u0 = bp[(size_t)(2 * jp) * HW];
        const uint u1 = bp[(size_t)(2 * jp + 1) * HW];
        u.w[jp] = u0 | (u1 << 16);
      }
      bfr[ni] = u.f;
    }
#pragma unroll
    for (int mi = 0; mi < 4; ++mi)
#pragma unroll
      for (int ni = 0; ni < 4; ++ni)
        acc[mi][ni] = __builtin_amdgcn_mfma_f32_16x16x32_bf16(afr[mi], bfr[ni], acc[mi][ni], 0, 0, 0);
  }
#pragma unroll
  for (int mi = 0; mi < 4; ++mi)
#pragma unroll
    for (int r = 0; r < 4; ++r) {
      const int o = o0 + mi * 16 + lg * 4 + r;
#pragma unroll
      for (int ni = 0; ni < 4; ++ni)
        out[((size_t)bg * C + o) * HW + (p0 + ni * 16 + lr)] = acc[mi][ni][r];
    }
}

// ---------------------------------------------------------------------------
extern "C" void kernel_launch(void* const* d_in, const int* in_sizes, int n_in,
                              void* d_out, int out_size, void* d_ws, size_t ws_size,
                              hipStream_t stream) {
  const float* x      = (const float*)d_in[0];
  const float* qkv_w  = (const float*)d_in[1];
  const float* dw_w   = (const float*)d_in[2];
  const float* proj_w = (const float*)d_in[3];
  const float* temp   = (const float*)d_in[4];
  float* out = (float*)d_out;
  float* ws = (float*)d_ws;
  float* G  = ws + WS_G;
  float* Nq = ws + WS_NQ;
  float* Nk = ws + WS_NK;
  float* M  = ws + WS_M;

  const size_t small = WS_END * sizeof(float);              // 743424 B
  const size_t unit = (size_t)OC3 * HW * 2 * sizeof(ushort); // raw+dw bf16 per batch = 150,994,944 B
  int nb = 1;
  if (ws_size >= small + 4 * unit) nb = 4;       // 604.7 MB — proven to fit (round 1 ran this tier)
  else if (ws_size >= small + 2 * unit) nb = 2;
  ushort* raw = (ushort*)((char*)d_ws + small);
  ushort* dwb = raw + (size_t)nb * OC3 * HW;

  // zero accumulators (G, Nq, Nk) — ws is poisoned before each call
  hipMemsetAsync(G, 0, (WS_M - WS_G) * sizeof(float), stream);

  for (int b0 = 0; b0 < BB; b0 += nb) {
    qkv_mfma_k<<<dim3(HW / 256, OC3 / 64, nb), 256, 0, stream>>>(x, qkv_w, raw, b0);
    dwconv_k<<<dim3(HH / DW_RPB, OC3, nb), 256, 0, stream>>>(raw, dw_w, dwb, Nq, Nk, b0);
    gram_mfma_k<<<dim3(32, NH, nb), 256, 0, stream>>>(dwb, G, b0);
    softmax_M_k<<<dim3(NH, nb), 256, 0, stream>>>(G, Nq, Nk, proj_w, temp, M, b0);
    out_mfma_k<<<dim3(HW / 256, C / 64, nb), 256, 0, stream>>>(dwb, M, out, b0);
  }
}